// Round 8
// baseline (1035.231 us; speedup 1.0000x reference)
//
#include <hip/hip_runtime.h>
#include <hip/hip_bf16.h>

#define TT    128
#define BATCH 1024
#define INDIM 512
#define HIDD  1024
#define NCLS  10

typedef __bf16 bf16x8 __attribute__((ext_vector_type(8)));
typedef float  f32x4  __attribute__((ext_vector_type(4)));
typedef unsigned short u16x8 __attribute__((ext_vector_type(8)));

__device__ __forceinline__ unsigned short bf16b(float f) {
    __hip_bfloat16 h = __float2bfloat16(f);
    return __builtin_bit_cast(unsigned short, h);
}

__device__ __forceinline__ float tanh_fast(float x) {
    float e = __expf(2.0f * x);
    return 1.0f - 2.0f * __builtin_amdgcn_rcpf(e + 1.0f);
}

#define WAITV(n) asm volatile("s_waitcnt vmcnt(" #n ")" ::: "memory")
#define BAR()    asm volatile("s_barrier" ::: "memory")

// ---------------------------------------------------------------------------
// Prep: W -> transposed bf16 hi/lo pairs (unchanged, verified R1-R7).
// ---------------------------------------------------------------------------
__global__ __launch_bounds__(256) void prep_kernel(
    const float* __restrict__ Whh, const float* __restrict__ Wxh,
    __hip_bfloat16* __restrict__ WhhT_hi, __hip_bfloat16* __restrict__ WhhT_lo,
    __hip_bfloat16* __restrict__ WxhT_hi, __hip_bfloat16* __restrict__ WxhT_lo)
{
    __shared__ float tl[64][68];
    int bid = blockIdx.x, tid = threadIdx.x;
    const float* src; int N, k0, n0, dstride;
    __hip_bfloat16 *dhi, *dlo;
    if (bid < 256) { src = Whh; N = 1024; k0 = (bid >> 4) << 6; n0 = (bid & 15) << 6;
                     dhi = WhhT_hi; dlo = WhhT_lo; dstride = 1024; }
    else { int b = bid - 256; src = Wxh; N = 1024; k0 = (b >> 4) << 6; n0 = (b & 15) << 6;
           dhi = WxhT_hi; dlo = WxhT_lo; dstride = 512; }

    int r = tid >> 2, c0 = (tid & 3) << 4;
    const float* s = src + (size_t)(k0 + r) * N + n0 + c0;
#pragma unroll
    for (int j = 0; j < 4; ++j)
        *(float4*)&tl[r][c0 + j * 4] = *(const float4*)(s + j * 4);
    __syncthreads();

    int rn = tid >> 2, ck0 = (tid & 3) << 4;
    u16x8 hi0, hi1, lo0, lo1;
#pragma unroll
    for (int j = 0; j < 16; ++j) {
        float w = tl[ck0 + j][rn];
        unsigned short hb = bf16b(w);
        float hf = __bfloat162float(__builtin_bit_cast(__hip_bfloat16, hb));
        unsigned short lb = bf16b(w - hf);
        if (j < 8) { hi0[j] = hb; lo0[j] = lb; }
        else       { hi1[j - 8] = hb; lo1[j - 8] = lb; }
    }
    size_t o = (size_t)(n0 + rn) * dstride + k0 + ck0;
    *(u16x8*)(void*)(dhi + o)     = hi0;
    *(u16x8*)(void*)(dhi + o + 8) = hi1;
    *(u16x8*)(void*)(dlo + o)     = lo0;
    *(u16x8*)(void*)(dlo + o + 8) = lo1;
}

// ---------------------------------------------------------------------------
__global__ __launch_bounds__(256) void convx_all_kernel(
    const float* __restrict__ x, __hip_bfloat16* __restrict__ xs)
{
    size_t gid = (size_t)blockIdx.x * 256 + threadIdx.x;
    int i  = (int)(gid & 63) << 3;
    size_t bt = gid >> 6;
    int t = (int)(bt & 127);
    int b = (int)(bt >> 7);
    const float* s = x + ((size_t)b * TT + t) * INDIM + i;
    float4 a0 = *(const float4*)s, a1 = *(const float4*)(s + 4);
    u16x8 o;
    o[0]=bf16b(a0.x); o[1]=bf16b(a0.y); o[2]=bf16b(a0.z); o[3]=bf16b(a0.w);
    o[4]=bf16b(a1.x); o[5]=bf16b(a1.y); o[6]=bf16b(a1.z); o[7]=bf16b(a1.w);
    *(u16x8*)(void*)(xs + ((size_t)t * BATCH + b) * INDIM + i) = o;
}

__global__ __launch_bounds__(256) void zero_kernel(
    __hip_bfloat16* __restrict__ h, unsigned* __restrict__ bar)
{
    if (blockIdx.x < 512) {
        size_t i = ((size_t)blockIdx.x * 256 + threadIdx.x) << 3;
        u16x8 z = {0,0,0,0,0,0,0,0};
        *(u16x8*)(void*)(h + i) = z;
    } else {
        uint4 z = {0,0,0,0};
#pragma unroll
        for (int k = 0; k < 8; ++k)
            ((uint4*)bar)[k * 256 + threadIdx.x] = z;
    }
}

// ---------------------------------------------------------------------------
// Persistent RNN, R8. Same region pipeline as R7 (8x16KB bufs, 5 BAR/step,
// counted vmcnt, x(t+1) prefetch). New: agent-scope flags (group is
// XCD-local) and ring-ordered just-in-time polls: h-chunk position p stages
// chunk ((bx>>1)+p)&7, polling ONLY its 2 producer blocks right before the
// STAGE. Bh weight frags are loaded pre-rotated at the prologue so position
// indexing into the register array stays compile-time (no scratch).
// ---------------------------------------------------------------------------
#define FRAGA(_b, m, ks) \
    (*(const bf16x8*)((_b) + ((((m)<<4)+ar) << 8) + ((((((ks)<<2)+kg)) ^ (ar & 7)) << 4)))

#define STAGE(basePtr, rs, bufidx, AUX) do {                                   \
    _Pragma("unroll")                                                          \
    for (int _i = 0; _i < 4; ++_i) {                                           \
        int _r = (_i << 4) + (tid >> 4);                                       \
        int _s = (tid & 15) ^ (_r & 7);                                        \
        const void* _g = (const void*)((basePtr) + (size_t)_r * (rs) + (_s << 3)); \
        void* _l = (void*)(smem + ((bufidx) << 14) + (_i << 12) + (wave << 10));   \
        __builtin_amdgcn_global_load_lds(                                      \
            (const __attribute__((address_space(1))) void*)_g,                 \
            (__attribute__((address_space(3))) void*)_l, 16, 0, AUX);          \
    } } while (0)

#define DO_CHUNK(B_ARR, q, bufidx) do {                                        \
    const char* _b = smem + ((bufidx) << 14);                                  \
    _Pragma("unroll")                                                          \
    for (int ks = 0; ks < 4; ++ks) {                                           \
        bf16x8 a0 = FRAGA(_b, 0, ks), a1 = FRAGA(_b, 1, ks);                   \
        bf16x8 a2 = FRAGA(_b, 2, ks), a3 = FRAGA(_b, 3, ks);                   \
        bf16x8 bh = B_ARR[(q)*8+ks*2+0], bl = B_ARR[(q)*8+ks*2+1];             \
        acc0 = __builtin_amdgcn_mfma_f32_16x16x32_bf16(a0, bh, acc0, 0,0,0);   \
        acc1 = __builtin_amdgcn_mfma_f32_16x16x32_bf16(a1, bh, acc1, 0,0,0);   \
        acc2 = __builtin_amdgcn_mfma_f32_16x16x32_bf16(a2, bh, acc2, 0,0,0);   \
        acc3 = __builtin_amdgcn_mfma_f32_16x16x32_bf16(a3, bh, acc3, 0,0,0);   \
        acc0 = __builtin_amdgcn_mfma_f32_16x16x32_bf16(a0, bl, acc0, 0,0,0);   \
        acc1 = __builtin_amdgcn_mfma_f32_16x16x32_bf16(a1, bl, acc1, 0,0,0);   \
        acc2 = __builtin_amdgcn_mfma_f32_16x16x32_bf16(a2, bl, acc2, 0,0,0);   \
        acc3 = __builtin_amdgcn_mfma_f32_16x16x32_bf16(a3, bl, acc3, 0,0,0);   \
    } } while (0)

// JIT poll: wait until h-chunk `c_`'s two producer blocks (2c, 2c+1) have
// released step t. All 64 lanes participate (32 per flag); agent scope = L2.
#define POLL(c_) do { if (t > 0) {                                             \
    unsigned _s = (((unsigned)(c_)) << 1) | (lane & 1);                        \
    while (!__all(__hip_atomic_load(grpflags + (_s << 5), __ATOMIC_RELAXED,    \
                                    __HIP_MEMORY_SCOPE_AGENT) >= (unsigned)t)) \
        __builtin_amdgcn_s_sleep(1);                                           \
} } while (0)

__global__ __launch_bounds__(256, 1) void rnn_kernel(
    __hip_bfloat16* __restrict__ h0, __hip_bfloat16* __restrict__ h1,
    const __hip_bfloat16* __restrict__ xs,
    const __hip_bfloat16* __restrict__ WhhT_hi, const __hip_bfloat16* __restrict__ WhhT_lo,
    const __hip_bfloat16* __restrict__ WxhT_hi, const __hip_bfloat16* __restrict__ WxhT_lo,
    const float* __restrict__ b_xh, const float* __restrict__ b_hh,
    unsigned* __restrict__ bar)
{
    __shared__ char smem[131072];                // 8 x 16KB staging buffers
    int tid = threadIdx.x, bid = blockIdx.x;
    // XCD-local by-groups (proven R6): bid%8 = XCD.
    int by = (bid & 7) | (((bid >> 3) & 1) << 3);
    int bx = bid >> 4;
    int lane = tid & 63, wave = tid >> 6;
    int ar = lane & 15, kg = lane >> 4;
    int wcol = (bx << 6) + (wave << 4);
    int by64 = by << 6;
    int rb = bx >> 1;                            // ring start = own col-chunk

    // ---- weights to registers. Bh is loaded PRE-ROTATED: slot c holds the
    // frags for h-chunk ((bx>>1)+c)&7, so ring position indexing is static.
    bf16x8 Bh[64], Bx[32];
    {
        const __hip_bfloat16* hiB = WhhT_hi + (size_t)(wcol + ar) * HIDD + (kg << 3);
        const __hip_bfloat16* loB = WhhT_lo + (size_t)(wcol + ar) * HIDD + (kg << 3);
#pragma unroll
        for (int c = 0; c < 8; ++c) {
            int cc = (rb + c) & 7;
#pragma unroll
            for (int ks = 0; ks < 4; ++ks) {
                Bh[c*8 + ks*2 + 0] = *(const bf16x8*)(hiB + cc*128 + ks*32);
                Bh[c*8 + ks*2 + 1] = *(const bf16x8*)(loB + cc*128 + ks*32);
            }
        }
        const __hip_bfloat16* hiX = WxhT_hi + (size_t)(wcol + ar) * INDIM + (kg << 3);
        const __hip_bfloat16* loX = WxhT_lo + (size_t)(wcol + ar) * INDIM + (kg << 3);
#pragma unroll
        for (int c = 0; c < 4; ++c)
#pragma unroll
            for (int ks = 0; ks < 4; ++ks) {
                Bx[c*8 + ks*2 + 0] = *(const bf16x8*)(hiX + c*128 + ks*32);
                Bx[c*8 + ks*2 + 1] = *(const bf16x8*)(loX + c*128 + ks*32);
            }
    }
    int mycol = wcol + ar;
    float bias = b_xh[mycol] + b_hh[mycol];

    unsigned* grpflags = bar + (by << 9);
    unsigned* myflag   = grpflags + (bx << 5);

    // Prologue: stage x(0): x0->b2, x1->b3, x2->b0, x3->b1.
    {
        const __hip_bfloat16* xA0 = xs + (size_t)by64 * INDIM;
        STAGE(xA0 + 0*128, INDIM, 2, 0);
        STAGE(xA0 + 1*128, INDIM, 3, 0);
        STAGE(xA0 + 2*128, INDIM, 0, 0);
        STAGE(xA0 + 3*128, INDIM, 1, 0);
    }
    WAITV(0); BAR();                             // weights + x(0) all in

    for (int t = 0; t < TT; ++t) {
        const __hip_bfloat16* hA = (t & 1) ? h1 : h0;
        __hip_bfloat16*       hB = (t & 1) ? h0 : h1;
        const __hip_bfloat16* hR = hA + (size_t)by64 * HIDD;
        const __hip_bfloat16* xN = xs + (size_t)(t + 1) * (BATCH * INDIM)
                                      + (size_t)by64 * INDIM;   // x(t+1)
        int nl = (t < TT - 1);

        f32x4 acc0 = {0,0,0,0}, acc1 = {0,0,0,0}, acc2 = {0,0,0,0}, acc3 = {0,0,0,0};

        // ===== region 1: x-compute, 4 chunks, barrier-free ==================
        DO_CHUNK(Bx, 0, 2);
        DO_CHUNK(Bx, 1, 3);
        DO_CHUNK(Bx, 2, 0);
        DO_CHUNK(Bx, 3, 1);
        BAR();                                   // hand off b0-b3 for re-use

        // ===== h-phase: ring-ordered JIT polls + stage, then compute ========
        // position p stages h-chunk (rb+p)&7; weights are pre-rotated.
        POLL((rb + 0) & 7); STAGE(hR + (size_t)(((rb + 0) & 7) << 7), HIDD, 4, 1);
        POLL((rb + 1) & 7); STAGE(hR + (size_t)(((rb + 1) & 7) << 7), HIDD, 5, 1);
        POLL((rb + 2) & 7); STAGE(hR + (size_t)(((rb + 2) & 7) << 7), HIDD, 6, 1);
        POLL((rb + 3) & 7); STAGE(hR + (size_t)(((rb + 3) & 7) << 7), HIDD, 7, 1);
        POLL((rb + 4) & 7); STAGE(hR + (size_t)(((rb + 4) & 7) << 7), HIDD, 0, 1);
        POLL((rb + 5) & 7); STAGE(hR + (size_t)(((rb + 5) & 7) << 7), HIDD, 1, 1);
        if (nl) {
            STAGE(xN + 0*128, INDIM, 2, 0);      // x0' -> b2 (long flight)
            STAGE(xN + 1*128, INDIM, 3, 0);      // x1' -> b3
            WAITV(16);                           // positions 0-3 retired
        } else {
            WAITV(8);
        }
        BAR();
        DO_CHUNK(Bh, 0, 4);                      // 4 chunks barrier-free
        DO_CHUNK(Bh, 1, 5);
        DO_CHUNK(Bh, 2, 6);
        DO_CHUNK(Bh, 3, 7);
        if (nl) { WAITV(8); } else { WAITV(0); } // positions 4,5 retired
        BAR();                                   // b6,b7 readers done
        POLL((rb + 6) & 7); STAGE(hR + (size_t)(((rb + 6) & 7) << 7), HIDD, 6, 1);
        POLL((rb + 7) & 7); STAGE(hR + (size_t)(((rb + 7) & 7) << 7), HIDD, 7, 1);
        DO_CHUNK(Bh, 4, 0);
        DO_CHUNK(Bh, 5, 1);
        WAITV(0);                                // positions 6,7 in
        BAR();                                   // b0,b1 readers done
        if (nl) {
            STAGE(xN + 2*128, INDIM, 0, 0);      // x2' -> b0
            STAGE(xN + 3*128, INDIM, 1, 0);      // x3' -> b1
        }
        DO_CHUNK(Bh, 6, 6);
        DO_CHUNK(Bh, 7, 7);

        // ===== epilogue + release ==========================================
#pragma unroll
        for (int m = 0; m < 4; ++m) {
            f32x4 a = (m == 0) ? acc0 : (m == 1) ? acc1 : (m == 2) ? acc2 : acc3;
#pragma unroll
            for (int j = 0; j < 4; ++j) {
                int row = by64 + (m << 4) + (kg << 2) + j;
                float v = tanh_fast(a[j] + bias);
                hB[(size_t)row * HIDD + mycol] = __float2bfloat16(v);
            }
        }
        WAITV(0);                                // h stores + x2',x3' drained
        BAR();                                   // all threads' stores done
        if (nl && tid == 0)
            __hip_atomic_store(myflag, (unsigned)(t + 1), __ATOMIC_RELAXED,
                               __HIP_MEMORY_SCOPE_AGENT);
    }
}

// ---------------------------------------------------------------------------
__global__ __launch_bounds__(64) void out_kernel(
    const __hip_bfloat16* __restrict__ h, const float* __restrict__ Why,
    const float* __restrict__ b_y, float* __restrict__ out)
{
    int b = blockIdx.x, lane = threadIdx.x;
    float acc[NCLS];
#pragma unroll
    for (int c = 0; c < NCLS; ++c) acc[c] = 0.f;
    for (int kk = 0; kk < 16; ++kk) {
        int k = (kk << 6) + lane;
        float hv = __bfloat162float(h[(size_t)b * HIDD + k]);
#pragma unroll
        for (int c = 0; c < NCLS; ++c) acc[c] += hv * Why[(size_t)k * NCLS + c];
    }
#pragma unroll
    for (int c = 0; c < NCLS; ++c) {
        float v = acc[c];
#pragma unroll
        for (int off = 32; off > 0; off >>= 1) v += __shfl_down(v, off);
        if (lane == 0) out[(size_t)b * NCLS + c] = v + b_y[c];
    }
}

// ---------------------------------------------------------------------------
extern "C" void kernel_launch(void* const* d_in, const int* in_sizes, int n_in,
                              void* d_out, int out_size, void* d_ws, size_t ws_size,
                              hipStream_t stream)
{
    const float* x    = (const float*)d_in[0];
    const float* Wxh  = (const float*)d_in[1];
    const float* b_xh = (const float*)d_in[2];
    const float* Whh  = (const float*)d_in[3];
    const float* b_hh = (const float*)d_in[4];
    const float* Why  = (const float*)d_in[5];
    const float* b_y  = (const float*)d_in[6];
    float* out = (float*)d_out;

    char* ws = (char*)d_ws;                       // 144 MB used
    __hip_bfloat16* WhhT_hi = (__hip_bfloat16*)(ws);
    __hip_bfloat16* WhhT_lo = (__hip_bfloat16*)(ws + (2u  << 20));
    __hip_bfloat16* WxhT_hi = (__hip_bfloat16*)(ws + (4u  << 20));
    __hip_bfloat16* WxhT_lo = (__hip_bfloat16*)(ws + (5u  << 20));
    __hip_bfloat16* h0      = (__hip_bfloat16*)(ws + (6u  << 20));
    __hip_bfloat16* h1      = (__hip_bfloat16*)(ws + (8u  << 20));
    unsigned*       bar     = (unsigned*)      (ws + (10u << 20));
    __hip_bfloat16* xs      = (__hip_bfloat16*)(ws + (16u << 20));  // 128 MB

    prep_kernel<<<384, 256, 0, stream>>>(Whh, Wxh, WhhT_hi, WhhT_lo, WxhT_hi, WxhT_lo);
    convx_all_kernel<<<32768, 256, 0, stream>>>(x, xs);
    zero_kernel<<<513, 256, 0, stream>>>(h0, bar);

    rnn_kernel<<<256, 256, 0, stream>>>(h0, h1, xs,
                                        WhhT_hi, WhhT_lo, WxhT_hi, WxhT_lo,
                                        b_xh, b_hh, bar);

    out_kernel<<<1024, 64, 0, stream>>>(h0, Why, b_y, out);  // final h is in h0
}